// Round 12
// baseline (62.262 us; speedup 1.0000x reference)
//
#include <hip/hip_runtime.h>

// QuantizedConv1d on MI355X (gfx950) — round 12: pre-quantized, pre-swizzled
// global xqs + global_load_lds linear staging.
// B=32, CIN=128, L=4096, COUT=256, K=5, replication pad 2.
//   prep_kernel: x f32 -> xqs i8 [B][4104 rows][128 ci], rows = gl+4 clamped
//                (replication pad), in-row 16B chunks stored at XOR-swizzled
//                slots (chunk ^ (row&7)) — valid for every 128-aligned tile.
//                Also W -> fragment-linear i8 wtf + requant table.
//   conv_fused:  stage = linear 17,408B copy via 17 global_load_lds (no VALU,
//                no regs); K-loop/epilogue = round-11 verified i8 MFMA path.
// Round-11 post-mortem: VALUBusy 24% (in-conv quantize, duplicated per
// cohalf) was the largest consumer; nothing saturated. Split quant out.

#define B_    32
#define CIN   128
#define LEN   4096
#define COUT  256
#define KW    5
#define RPAD  4104   // padded rows per batch: row = gl+4, gl in [-4, 4100)
#define TROWS 136    // staged rows per 128-l tile

#define XQS_BYTES ((size_t)B_ * RPAD * CIN)   // 16,809,984
#define WTF_BYTES (KW * 2 * 16 * 64 * 16)     // 163,840

typedef int          i32x4 __attribute__((ext_vector_type(4)));
typedef float        f32x4 __attribute__((ext_vector_type(4)));
typedef signed char  s8;
typedef unsigned int u32;

// round-half-even(x*20) - 3, clip to [-128,127], as int8.
// (x*20f vs x/0.05f: <=1ulp flips ~1e-6/elem, each moves an output <=0.64 —
// inside the 2.56 absmax threshold; validated passing rounds 6/8/9/10/11.)
__device__ __forceinline__ s8 quant_i8(float xv) {
    float q = rintf(xv * 20.0f) - 3.0f;
    q = fminf(fmaxf(q, -128.0f), 127.0f);
    return (s8)(int)q;
}

// Grid 584 = 544 xq-blocks + 40 w-blocks, 256 threads.
__global__ __launch_bounds__(256) void prep_kernel(
        const float* __restrict__ x, const int* __restrict__ w,
        const int* __restrict__ bias, const float* __restrict__ wscale,
        s8* __restrict__ xqs, s8* __restrict__ wtf, float* __restrict__ tbl)
{
    int bx = blockIdx.x, tid = threadIdx.x;
    if (bx < 544) {
        // ---- X: quantize + transpose into pre-swizzled xqs ----
        // Thread = (rowquad rq, chunk c): rows 4rq..4rq+3, ci c*16..c*16+15.
        // Lanes consecutive in rq -> f32x4 loads are 1KB contiguous per j.
        int b = bx / 17, rg = bx % 17;
        int lane = tid & 63, wv = tid >> 6;
        int rq = rg * 64 + lane;              // 0..1087 (1026 valid)
        if (rq >= 1026) return;
        int r0 = rq << 2;
        const float* xbb = x + (size_t)b * CIN * LEN;
        bool interior = (rq >= 1) && (rq <= 1024);
        #pragma unroll
        for (int it = 0; it < 2; ++it) {
            int c = wv + (it << 2);           // chunk 0..7
            union { s8 cc[16]; i32x4 v; } q[4];
            if (interior) {
                const float* src = xbb + (size_t)(c << 4) * LEN + (r0 - 4);
                #pragma unroll
                for (int j = 0; j < 16; ++j) {
                    f32x4 f = *(const f32x4*)(src + (size_t)j * LEN);
                    #pragma unroll
                    for (int m = 0; m < 4; ++m) q[m].cc[j] = quant_i8(f[m]);
                }
            } else {
                #pragma unroll
                for (int j = 0; j < 16; ++j)
                    #pragma unroll
                    for (int m = 0; m < 4; ++m) {
                        int gl = r0 + m - 4;
                        gl = min(max(gl, 0), LEN - 1);
                        q[m].cc[j] = quant_i8(xbb[(size_t)((c << 4) + j) * LEN + gl]);
                    }
            }
            #pragma unroll
            for (int m = 0; m < 4; ++m) {
                int r = r0 + m;
                *(i32x4*)(xqs + ((size_t)b * RPAD + r) * CIN + ((c ^ (r & 7)) << 4)) = q[m].v;
            }
        }
    } else {
        // ---- W -> fragment-linear i8: frag = k*32 + s*16 + co16; lane holds
        // W[co16*16 + (lane&15)][ci = s*64 + (lane>>4)*16 + j], j=0..15.
        int o    = (bx - 544) * 256 + tid;    // 0..10239
        int lane = o & 63, frag = o >> 6;     // frag 0..159
        int k    = frag >> 5;
        int s    = (frag >> 4) & 1;
        int co   = ((frag & 15) << 4) + (lane & 15);
        int ci   = (s << 6) + ((lane >> 4) << 4);
        union { s8 c[16]; i32x4 v; } q;
        #pragma unroll
        for (int j = 0; j < 16; ++j)
            q.c[j] = (s8)w[co * (CIN * KW) + (ci + j) * KW + k];   // |v|<=127
        *(i32x4*)(wtf + (size_t)frag * 1024 + lane * 16) = q.v;

        if (bx == 544) {                      // requant table: sc, off
            int c = tid;                      // 0..255
            float sc = __fdiv_rn(__fmul_rn(0.05f, wscale[c]), 0.1f);
            tbl[c]       = sc;
            tbl[256 + c] = fmaf((float)bias[c], sc, -128.0f);
        }
    }
}

// Block: 128 co x 128 l, 256 threads, 4 waves = 2co x 2l; wave = 64co x 64l.
// LDS: [136 rows][128 ci] i8, 17,408 B — loaded as a LINEAR copy of the
// pre-swizzled xqs tile (rows l0..l0+135 are contiguous). Swizzle identity:
// xqs row r slot = c^(r&7); LDS row = r-l0, l0 % 128 == 0 -> same (row&7).
// Grid 2048 = B x ltile x cohalf, XCD-chunked remap. 4 blocks/CU.
__global__ __launch_bounds__(256, 4) void conv_fused(
        const s8* __restrict__ xqs, const s8* __restrict__ wtf,
        const float* __restrict__ tbl, int* __restrict__ out)
{
    __shared__ __align__(16) s8 smem[TROWS * CIN];   // 17,408 B

    // XCD-contiguous bijective remap (2048 = 8 XCDs x 256): cohalf pairs are
    // consecutive orig ids -> same XCD, adjacent in time (X tile L2 hit).
    int orig  = (blockIdx.x & 7) * 256 + (blockIdx.x >> 3);
    int ch    = orig & 1;
    int ltile = (orig >> 1) & 31;
    int b     = orig >> 6;
    int l0    = ltile << 7;
    int tid   = threadIdx.x;
    int wid   = tid >> 6, lane = tid & 63;
    int lr    = lane & 15, lh = lane >> 4;
    int cog   = (ch << 7) + ((wid & 1) << 6);   // wave co base
    int wl    = (wid >> 1) << 6;                // wave local-l base {0,64}

    // ---- stage: linear 17,408B tile copy, 17 global_load_lds (width 16).
    // LDS dst = wave-uniform base + lane*16 (HW); global src per-lane linear.
    const s8* src = xqs + ((size_t)b * RPAD + l0) * CIN;
    for (int i = wid; i < 17; i += 4)
        __builtin_amdgcn_global_load_lds(
            (const __attribute__((address_space(1))) u32*)(src + (i << 10) + (lane << 4)),
            (__attribute__((address_space(3))) u32*)(smem + (i << 10)),
            16, 0, 0);
    __syncthreads();

    // ---- K-loop: 5 taps x 2 ci-halves; 4 af (1KB coalesced, L2-resident) +
    // 4 bf (conflict-free b128) -> 16 mfma_i32_16x16x64_i8.
    // SWAPPED operands (A=X row=l, B=W col=co): D col=co, row=l.
    i32x4 acc[4][4] = {};
    #pragma unroll
    for (int k = 0; k < KW; ++k) {
        #pragma unroll
        for (int s = 0; s < 2; ++s) {
            i32x4 af[4];
            #pragma unroll
            for (int ct = 0; ct < 4; ++ct)
                af[ct] = *(const i32x4*)(
                    wtf + (size_t)((k << 5) + (s << 4) + (cog >> 4) + ct) * 1024 + lane * 16);
            i32x4 bf[4];
            int chunk = (s << 2) + lh;
            #pragma unroll
            for (int lt = 0; lt < 4; ++lt) {
                int row = wl + (lt << 4) + lr + k + 2;
                bf[lt] = *(const i32x4*)(smem + (row << 7) + ((chunk ^ (row & 7)) << 4));
            }
            #pragma unroll
            for (int ct = 0; ct < 4; ++ct)
                #pragma unroll
                for (int lt = 0; lt < 4; ++lt)
                    acc[ct][lt] = __builtin_amdgcn_mfma_i32_16x16x64_i8(
                        bf[lt], af[ct], acc[ct][lt], 0, 0, 0);
        }
    }

    // ---- requant epilogue: col=co=cog+ct*16+lr (per-lane sc/off), row=l.
    // acc[ct][lt] = 4 consecutive l at fixed co -> one dwordx4 store each.
    // (float)int32 is exact (|sum| <= 10.3M < 2^24).
    size_t outb = (size_t)b * COUT * LEN;
    #pragma unroll
    for (int ct = 0; ct < 4; ++ct) {
        int co = cog + (ct << 4) + lr;
        float scv = tbl[co];
        float off = tbl[256 + co];
        int* orow = out + outb + (size_t)co * LEN + l0 + wl + (lh << 2);
        #pragma unroll
        for (int lt = 0; lt < 4; ++lt) {
            i32x4 pk;
            #pragma unroll
            for (int r = 0; r < 4; ++r) {
                float o = rintf(fmaf((float)acc[ct][lt][r], scv, off));
                o = fminf(fmaxf(o, -128.0f), 127.0f);
                pk[r] = (int)o;
            }
            *(i32x4*)(orow + (lt << 4)) = pk;
        }
    }
}

extern "C" void kernel_launch(void* const* d_in, const int* in_sizes, int n_in,
                              void* d_out, int out_size, void* d_ws, size_t ws_size,
                              hipStream_t stream)
{
    const float* x    = (const float*)d_in[0];
    const int*   w    = (const int*)d_in[1];
    const int*   bias = (const int*)d_in[2];
    const float* wsc  = (const float*)d_in[3];
    int* out = (int*)d_out;

    s8*    xqs = (s8*)d_ws;                    // 16,809,984 B
    s8*    wtf = xqs + XQS_BYTES;              // +163,840 B
    float* tbl = (float*)(wtf + WTF_BYTES);    // +2 KB   (total ~17.0 MB)

    prep_kernel<<<dim3(584), dim3(256), 0, stream>>>(x, w, bias, wsc, xqs, wtf, tbl);
    conv_fused<<<dim3(2048), dim3(256), 0, stream>>>(xqs, wtf, tbl, out);
}